// Round 1
// baseline (524.958 us; speedup 1.0000x reference)
//
#include <hip/hip_runtime.h>
#include <hip/hip_bf16.h>

#define PAD_VALUE -1000.0f

// Problem constants (from reference setup_inputs)
constexpr int B   = 4;
constexpr int T   = 24;
constexpr int C   = 10;
constexpr int H   = 128;
constexpr int W   = 128;
constexpr int Tc  = 365;
constexpr int Dc  = 11;
constexpr int HID = 64;
constexpr int Dm  = 64;
constexpr int HW  = H * W;     // 16384
constexpr int CO  = C + Dm;    // 74 output channels

// Native clang vector type — __builtin_nontemporal_* requires a real vector,
// not HIP's struct-wrapped float4.
typedef float vfloat4 __attribute__((ext_vector_type(4)));

// ---------------------------------------------------------------------------
// Kernel 1: per (b,t) date match + tiny MLP -> clim_feat[B*T][64] fp32.
// One block per (b,t), 64 threads. All float tensors are FP32.
// Dates may arrive as int32 or int64; autodetect (int64 => all odd 32-bit
// words of dates_sat are 0, since values < 365 and nonnegative).
// ---------------------------------------------------------------------------
__global__ void clim_mlp_kernel(const int* __restrict__ dates_sat_raw,   // [B*T] (i32 or i64)
                                const float* __restrict__ input_clim,    // [B*Tc*Dc]
                                const int* __restrict__ dates_clim_raw,  // [B*Tc] (i32 or i64)
                                const float* __restrict__ W1,            // [Dc*HID]
                                const float* __restrict__ b1,            // [HID]
                                const float* __restrict__ W2,            // [HID*Dm]
                                const float* __restrict__ b2,            // [Dm]
                                float* __restrict__ feat_out) {          // [B*T*Dm] fp32
    const int bt  = blockIdx.x;         // 0..B*T-1
    const int b   = bt / T;
    const int tid = threadIdx.x;        // 0..63

    __shared__ int   s_idx;
    __shared__ int   s_is64;
    __shared__ float s_clim[Dc];
    __shared__ float s_h[HID];

    if (tid == 0) {
        s_idx = 0x7fffffff;
        int is64 = 1;
        for (int i = 1; i < B * T; i += 2) {
            if (dates_sat_raw[i] != 0) { is64 = 0; break; }
        }
        s_is64 = is64;
    }
    __syncthreads();
    const int is64 = s_is64;

    const int target = is64 ? dates_sat_raw[2 * bt] : dates_sat_raw[bt];

    // first climate index whose date equals the sat date
    int local = 0x7fffffff;
    for (int j = tid; j < Tc; j += 64) {
        const int e = b * Tc + j;
        const int dc = is64 ? dates_clim_raw[2 * e] : dates_clim_raw[e];
        if (dc == target) local = min(local, j);
    }
    if (local != 0x7fffffff) atomicMin(&s_idx, local);
    __syncthreads();

    const int  idx = s_idx;
    const bool has = idx < Tc;

    if (tid < Dc) {
        s_clim[tid] = has ? input_clim[(b * Tc + idx) * Dc + tid] : PAD_VALUE;
    }
    __syncthreads();

    // hidden layer: h[tid] = relu(sum_d clim[d]*W1[d][tid] + b1[tid])
    float acc = b1[tid];
#pragma unroll
    for (int d = 0; d < Dc; ++d)
        acc += s_clim[d] * W1[d * HID + tid];
    s_h[tid] = fmaxf(acc, 0.0f);
    __syncthreads();

    // output layer: feat[tid] = sum_j h[j]*W2[j][tid] + b2[tid]
    float acc2 = b2[tid];
#pragma unroll
    for (int j = 0; j < HID; ++j)
        acc2 += s_h[j] * W2[j * Dm + tid];

    feat_out[bt * Dm + tid] = acc2;
}

// ---------------------------------------------------------------------------
// Kernel 2: assemble output [B,T,74,H,W] fp32.
// One block per (b,t,c) plane of 16384 floats; 256 threads x 16 iters of
// 16 B/lane stores.
//
// A/B vs previous round: stores switched from __builtin_nontemporal_store
// (bypass L2) to REGULAR stores (L2 write-allocate, full-line evict).
// Evidence: harness fillBufferAligned achieves 6.4 TB/s on the same buffer
// with regular stores and FETCH_SIZE≈0 (no RFO for full-line streaming
// writes), while this kernel was running at ~2.4 TB/s effective with NT
// stores. Loads stay nontemporal to keep this a single-variable experiment.
// ---------------------------------------------------------------------------
__global__ __launch_bounds__(256)
void assemble_kernel(const float* __restrict__ input_sat,  // [B*T*C*HW] fp32
                     const float* __restrict__ feat,       // [B*T*Dm] fp32
                     float* __restrict__ out) {            // [B*T*CO*HW] fp32
    const int plane = blockIdx.x;       // 0 .. B*T*CO-1
    const int c  = plane % CO;
    const int bt = plane / CO;

    vfloat4* __restrict__ dst4 = reinterpret_cast<vfloat4*>(out + (size_t)plane * HW);
    constexpr int NVEC = HW / 4;        // 4096 float4 per plane

    if (c < C) {
        const vfloat4* __restrict__ src4 = reinterpret_cast<const vfloat4*>(
            input_sat + (size_t)(bt * C + c) * HW);
#pragma unroll 4
        for (int i = threadIdx.x; i < NVEC; i += 256) {
            const vfloat4 v = __builtin_nontemporal_load(&src4[i]);
            dst4[i] = v;
        }
    } else {
        const float v = feat[bt * Dm + (c - C)];
        const vfloat4 splat = {v, v, v, v};
#pragma unroll 4
        for (int i = threadIdx.x; i < NVEC; i += 256)
            dst4[i] = splat;
    }
}

// ---------------------------------------------------------------------------
extern "C" void kernel_launch(void* const* d_in, const int* in_sizes, int n_in,
                              void* d_out, int out_size, void* d_ws, size_t ws_size,
                              hipStream_t stream) {
    const float* input_sat  = (const float*)d_in[0];
    const int*   dates_sat  = (const int*)d_in[1];
    const float* input_clim = (const float*)d_in[2];
    const int*   dates_clim = (const int*)d_in[3];
    const float* W1p        = (const float*)d_in[4];
    const float* b1p        = (const float*)d_in[5];
    const float* W2p        = (const float*)d_in[6];
    const float* b2p        = (const float*)d_in[7];

    float* feat = (float*)d_ws;    // B*T*Dm fp32 (24 KB scratch)
    float* out  = (float*)d_out;   // fp32 output (reference output dtype)

    clim_mlp_kernel<<<B * T, 64, 0, stream>>>(dates_sat, input_clim, dates_clim,
                                              W1p, b1p, W2p, b2p, feat);

    assemble_kernel<<<B * T * CO, 256, 0, stream>>>(input_sat, feat, out);
}

// Round 2
// 522.914 us; speedup vs baseline: 1.0039x; 1.0039x over previous
//
#include <hip/hip_runtime.h>
#include <hip/hip_bf16.h>

#define PAD_VALUE -1000.0f

// Problem constants (from reference setup_inputs)
constexpr int B   = 4;
constexpr int T   = 24;
constexpr int C   = 10;
constexpr int H   = 128;
constexpr int W   = 128;
constexpr int Tc  = 365;
constexpr int Dc  = 11;
constexpr int HID = 64;
constexpr int Dm  = 64;
constexpr int HW  = H * W;     // 16384
constexpr int CO  = C + Dm;    // 74 output channels
constexpr int NPLANES = B * T * CO;  // 7104

// Native clang vector type — __builtin_nontemporal_* requires a real vector,
// not HIP's struct-wrapped float4.
typedef float vfloat4 __attribute__((ext_vector_type(4)));

// ---------------------------------------------------------------------------
// Kernel 1: per (b,t) date match + tiny MLP -> clim_feat[B*T][64] fp32.
// One block per (b,t), 64 threads. All float tensors are FP32.
//
// R2 change: int64-vs-int32 date autodetect was a SERIAL 48-load loop run by
// thread 0 of every block (~18 µs of dependent cold misses, 63 lanes idle).
// Now: 48 lanes each load one odd 32-bit word in parallel, one __ballot.
// (int64 => all odd 32-bit words of dates_sat are 0, values < 365, >= 0.)
// ---------------------------------------------------------------------------
__global__ void clim_mlp_kernel(const int* __restrict__ dates_sat_raw,   // [B*T] (i32 or i64)
                                const float* __restrict__ input_clim,    // [B*Tc*Dc]
                                const int* __restrict__ dates_clim_raw,  // [B*Tc] (i32 or i64)
                                const float* __restrict__ W1,            // [Dc*HID]
                                const float* __restrict__ b1,            // [HID]
                                const float* __restrict__ W2,            // [HID*Dm]
                                const float* __restrict__ b2,            // [Dm]
                                float* __restrict__ feat_out) {          // [B*T*Dm] fp32
    const int bt  = blockIdx.x;         // 0..B*T-1
    const int b   = bt / T;
    const int tid = threadIdx.x;        // 0..63

    __shared__ int   s_idx;
    __shared__ float s_clim[Dc];
    __shared__ float s_h[HID];

    if (tid == 0) s_idx = 0x7fffffff;

    // Parallel dtype autodetect: one load per lane, one 64-bit ballot.
    int oddword = 0;
    if (tid < (B * T) / 2) oddword = dates_sat_raw[2 * tid + 1];
    const bool is64 = (__ballot(oddword != 0) == 0ull);

    __syncthreads();

    const int target = is64 ? dates_sat_raw[2 * bt] : dates_sat_raw[bt];

    // first climate index whose date equals the sat date
    int local = 0x7fffffff;
    for (int j = tid; j < Tc; j += 64) {
        const int e = b * Tc + j;
        const int dc = is64 ? dates_clim_raw[2 * e] : dates_clim_raw[e];
        if (dc == target) local = min(local, j);
    }
    if (local != 0x7fffffff) atomicMin(&s_idx, local);
    __syncthreads();

    const int  idx = s_idx;
    const bool has = idx < Tc;

    if (tid < Dc) {
        s_clim[tid] = has ? input_clim[(b * Tc + idx) * Dc + tid] : PAD_VALUE;
    }
    __syncthreads();

    // hidden layer: h[tid] = relu(sum_d clim[d]*W1[d][tid] + b1[tid])
    float acc = b1[tid];
#pragma unroll
    for (int d = 0; d < Dc; ++d)
        acc += s_clim[d] * W1[d * HID + tid];
    s_h[tid] = fmaxf(acc, 0.0f);
    __syncthreads();

    // output layer: feat[tid] = sum_j h[j]*W2[j][tid] + b2[tid]
    float acc2 = b2[tid];
#pragma unroll
    for (int j = 0; j < HID; ++j)
        acc2 += s_h[j] * W2[j * Dm + tid];

    feat_out[bt * Dm + tid] = acc2;
}

// ---------------------------------------------------------------------------
// Kernel 2: assemble output [B,T,74,H,W] fp32.
//
// R2 change: grid-stride persistent kernel at exactly 2048 blocks
// (8 blocks/CU x 256 CU at 4 waves/block = full 32-wave occupancy).
// The old 7104-block launch had 3.47 residency waves -> ~47%-occupied tail
// plus copy/splat block-cost imbalance. Grid-stride averages both out.
// Stores regular (R1 showed NT vs regular = null), loads stay NT.
// ---------------------------------------------------------------------------
__global__ __launch_bounds__(256)
void assemble_kernel(const float* __restrict__ input_sat,  // [B*T*C*HW] fp32
                     const float* __restrict__ feat,       // [B*T*Dm] fp32
                     float* __restrict__ out) {            // [B*T*CO*HW] fp32
    constexpr int NVEC = HW / 4;        // 4096 float4 per plane

    for (int plane = blockIdx.x; plane < NPLANES; plane += gridDim.x) {
        const int c  = plane % CO;
        const int bt = plane / CO;

        vfloat4* __restrict__ dst4 =
            reinterpret_cast<vfloat4*>(out + (size_t)plane * HW);

        if (c < C) {
            const vfloat4* __restrict__ src4 = reinterpret_cast<const vfloat4*>(
                input_sat + (size_t)(bt * C + c) * HW);
#pragma unroll 4
            for (int i = threadIdx.x; i < NVEC; i += 256) {
                const vfloat4 v = __builtin_nontemporal_load(&src4[i]);
                dst4[i] = v;
            }
        } else {
            const float v = feat[bt * Dm + (c - C)];
            const vfloat4 splat = {v, v, v, v};
#pragma unroll 4
            for (int i = threadIdx.x; i < NVEC; i += 256)
                dst4[i] = splat;
        }
    }
}

// ---------------------------------------------------------------------------
extern "C" void kernel_launch(void* const* d_in, const int* in_sizes, int n_in,
                              void* d_out, int out_size, void* d_ws, size_t ws_size,
                              hipStream_t stream) {
    const float* input_sat  = (const float*)d_in[0];
    const int*   dates_sat  = (const int*)d_in[1];
    const float* input_clim = (const float*)d_in[2];
    const int*   dates_clim = (const int*)d_in[3];
    const float* W1p        = (const float*)d_in[4];
    const float* b1p        = (const float*)d_in[5];
    const float* W2p        = (const float*)d_in[6];
    const float* b2p        = (const float*)d_in[7];

    float* feat = (float*)d_ws;    // B*T*Dm fp32 (24 KB scratch)
    float* out  = (float*)d_out;   // fp32 output (reference output dtype)

    clim_mlp_kernel<<<B * T, 64, 0, stream>>>(dates_sat, input_clim, dates_clim,
                                              W1p, b1p, W2p, b2p, feat);

    assemble_kernel<<<2048, 256, 0, stream>>>(input_sat, feat, out);
}

// Round 3
// 517.340 us; speedup vs baseline: 1.0147x; 1.0108x over previous
//
#include <hip/hip_runtime.h>
#include <hip/hip_bf16.h>

#define PAD_VALUE -1000.0f

// Problem constants (from reference setup_inputs)
constexpr int B   = 4;
constexpr int T   = 24;
constexpr int C   = 10;
constexpr int H   = 128;
constexpr int W   = 128;
constexpr int Tc  = 365;
constexpr int Dc  = 11;
constexpr int HID = 64;
constexpr int Dm  = 64;
constexpr int HW  = H * W;           // 16384
constexpr int CO  = C + Dm;          // 74 output channels
constexpr int NPLANES    = B * T * CO;          // 7104
constexpr int NVEC_PLANE = HW / 4;              // 4096 float4 per plane
constexpr int NVEC_TOTAL = NPLANES * NVEC_PLANE; // 29,097,984 (< 2^31)

typedef float vfloat4 __attribute__((ext_vector_type(4)));

// ---------------------------------------------------------------------------
// Kernel 1: per (b,t) date match + tiny MLP -> clim_feat[B*T][64] fp32.
// One block per (b,t), 64 threads. (unchanged from R2)
// ---------------------------------------------------------------------------
__global__ void clim_mlp_kernel(const int* __restrict__ dates_sat_raw,   // [B*T] (i32 or i64)
                                const float* __restrict__ input_clim,    // [B*Tc*Dc]
                                const int* __restrict__ dates_clim_raw,  // [B*Tc] (i32 or i64)
                                const float* __restrict__ W1,            // [Dc*HID]
                                const float* __restrict__ b1,            // [HID]
                                const float* __restrict__ W2,            // [HID*Dm]
                                const float* __restrict__ b2,            // [Dm]
                                float* __restrict__ feat_out) {          // [B*T*Dm] fp32
    const int bt  = blockIdx.x;         // 0..B*T-1
    const int b   = bt / T;
    const int tid = threadIdx.x;        // 0..63

    __shared__ int   s_idx;
    __shared__ float s_clim[Dc];
    __shared__ float s_h[HID];

    if (tid == 0) s_idx = 0x7fffffff;

    // Parallel dtype autodetect: one load per lane, one 64-bit ballot.
    // (int64 => all odd 32-bit words of dates_sat are 0, values in [0,365).)
    int oddword = 0;
    if (tid < (B * T) / 2) oddword = dates_sat_raw[2 * tid + 1];
    const bool is64 = (__ballot(oddword != 0) == 0ull);

    __syncthreads();

    const int target = is64 ? dates_sat_raw[2 * bt] : dates_sat_raw[bt];

    // first climate index whose date equals the sat date
    int local = 0x7fffffff;
    for (int j = tid; j < Tc; j += 64) {
        const int e = b * Tc + j;
        const int dc = is64 ? dates_clim_raw[2 * e] : dates_clim_raw[e];
        if (dc == target) local = min(local, j);
    }
    if (local != 0x7fffffff) atomicMin(&s_idx, local);
    __syncthreads();

    const int  idx = s_idx;
    const bool has = idx < Tc;

    if (tid < Dc) {
        s_clim[tid] = has ? input_clim[(b * Tc + idx) * Dc + tid] : PAD_VALUE;
    }
    __syncthreads();

    // hidden layer: h[tid] = relu(sum_d clim[d]*W1[d][tid] + b1[tid])
    float acc = b1[tid];
#pragma unroll
    for (int d = 0; d < Dc; ++d)
        acc += s_clim[d] * W1[d * HID + tid];
    s_h[tid] = fmaxf(acc, 0.0f);
    __syncthreads();

    // output layer: feat[tid] = sum_j h[j]*W2[j][tid] + b2[tid]
    float acc2 = b2[tid];
#pragma unroll
    for (int j = 0; j < HID; ++j)
        acc2 += s_h[j] * W2[j * Dm + tid];

    feat_out[bt * Dm + tid] = acc2;
}

// ---------------------------------------------------------------------------
// Kernel 2: assemble output [B,T,74,H,W] fp32.
//
// R3 change (kills the two remaining untested variables in one shot):
//  1) Work granularity: flat float4-index grid-stride over ALL 29.1M output
//     vectors instead of whole-64KB-plane granularity. Perfect balance
//     (55.5 vec/lane everywhere; the old scheme gave 960 blocks 4 planes and
//     1088 blocks 3 -> ~15% idle), consecutive lanes -> consecutive 16 B,
//     branch is wave-uniform except at 1-in-64 plane-boundary waves.
//  2) Load path: NT loads dropped (regular global loads). NT has been
//     constant since R0 and is the last untouched path flag.
// Stores regular (R1: NT-vs-regular null).
// ---------------------------------------------------------------------------
__global__ __launch_bounds__(256)
void assemble_kernel(const float* __restrict__ input_sat,  // [B*T*C*HW] fp32
                     const float* __restrict__ feat,       // [B*T*Dm] fp32
                     float* __restrict__ out) {            // [B*T*CO*HW] fp32
    const int stride = gridDim.x * 256;
    vfloat4* __restrict__ out4 = reinterpret_cast<vfloat4*>(out);
    const vfloat4* __restrict__ sat4 = reinterpret_cast<const vfloat4*>(input_sat);

    for (int g = blockIdx.x * 256 + threadIdx.x; g < NVEC_TOTAL; g += stride) {
        const int plane = g >> 12;           // g / 4096
        const int off   = g & 4095;
        const int c     = plane % CO;        // magic-mul, ~5 VALU
        const int bt    = plane / CO;

        if (c < C) {
            out4[g] = sat4[(bt * C + c) * NVEC_PLANE + off];
        } else {
            const float v = feat[bt * Dm + (c - C)];
            out4[g] = vfloat4{v, v, v, v};
        }
    }
}

// ---------------------------------------------------------------------------
extern "C" void kernel_launch(void* const* d_in, const int* in_sizes, int n_in,
                              void* d_out, int out_size, void* d_ws, size_t ws_size,
                              hipStream_t stream) {
    const float* input_sat  = (const float*)d_in[0];
    const int*   dates_sat  = (const int*)d_in[1];
    const float* input_clim = (const float*)d_in[2];
    const int*   dates_clim = (const int*)d_in[3];
    const float* W1p        = (const float*)d_in[4];
    const float* b1p        = (const float*)d_in[5];
    const float* W2p        = (const float*)d_in[6];
    const float* b2p        = (const float*)d_in[7];

    float* feat = (float*)d_ws;    // B*T*Dm fp32 (24 KB scratch)
    float* out  = (float*)d_out;   // fp32 output (reference output dtype)

    clim_mlp_kernel<<<B * T, 64, 0, stream>>>(dates_sat, input_clim, dates_clim,
                                              W1p, b1p, W2p, b2p, feat);

    assemble_kernel<<<2048, 256, 0, stream>>>(input_sat, feat, out);
}